// Round 1
// baseline (1733.351 us; speedup 1.0000x reference)
//
#include <hip/hip_runtime.h>
#include <math.h>

#define NNODES 100000

__device__ __forceinline__ float lrelu(float v) { return v > 0.f ? v : 0.2f * v; }

// ---------------- GEMM1: h1[N,64] = x[N,512] @ W1[512,64] ----------------
__global__ __launch_bounds__(256) void gemm1_k(const float* __restrict__ x,
                                               const float* __restrict__ W,
                                               float* __restrict__ h1, int Nn) {
    __shared__ float xs[64][65];
    __shared__ float ws[64][65];
    int r0 = blockIdx.x * 64;
    int t = threadIdx.x;
    int ty = t >> 4, tx = t & 15;
    float acc[4][4] = {};
    for (int kb = 0; kb < 512; kb += 64) {
        for (int l = t; l < 1024; l += 256) {
            int row = l >> 4;
            int c4 = (l & 15) * 4;
            int gr = r0 + row;
            float4 v = make_float4(0.f, 0.f, 0.f, 0.f);
            if (gr < Nn) v = *reinterpret_cast<const float4*>(&x[(size_t)gr * 512 + kb + c4]);
            xs[row][c4] = v.x; xs[row][c4 + 1] = v.y; xs[row][c4 + 2] = v.z; xs[row][c4 + 3] = v.w;
        }
        for (int l = t; l < 1024; l += 256) {
            int row = l >> 4;
            int c4 = (l & 15) * 4;
            float4 v = *reinterpret_cast<const float4*>(&W[(size_t)(kb + row) * 64 + c4]);
            ws[row][c4] = v.x; ws[row][c4 + 1] = v.y; ws[row][c4 + 2] = v.z; ws[row][c4 + 3] = v.w;
        }
        __syncthreads();
#pragma unroll
        for (int k = 0; k < 64; ++k) {
            float a[4], b[4];
#pragma unroll
            for (int i = 0; i < 4; ++i) a[i] = xs[ty * 4 + i][k];
#pragma unroll
            for (int j = 0; j < 4; ++j) b[j] = ws[k][tx * 4 + j];
#pragma unroll
            for (int i = 0; i < 4; ++i)
#pragma unroll
                for (int j = 0; j < 4; ++j) acc[i][j] += a[i] * b[j];
        }
        __syncthreads();
    }
#pragma unroll
    for (int i = 0; i < 4; ++i) {
        int gr = r0 + ty * 4 + i;
        if (gr < Nn) {
#pragma unroll
            for (int j = 0; j < 4; ++j) h1[(size_t)gr * 64 + tx * 4 + j] = acc[i][j];
        }
    }
}

// ---------------- GEMM2: h2[N,128] = h1a[N,64] @ W2[64,128] ----------------
__global__ __launch_bounds__(256) void gemm2_k(const float* __restrict__ xin,
                                               const float* __restrict__ W,
                                               float* __restrict__ h2, int Nn) {
    __shared__ float xs[64][65];
    __shared__ float ws[64][129];
    int r0 = blockIdx.x * 64;
    int t = threadIdx.x;
    int ty = t >> 4, tx = t & 15;
    // load x tile [64][64]
    for (int l = t; l < 1024; l += 256) {
        int row = l >> 4;
        int c4 = (l & 15) * 4;
        int gr = r0 + row;
        float4 v = make_float4(0.f, 0.f, 0.f, 0.f);
        if (gr < Nn) v = *reinterpret_cast<const float4*>(&xin[(size_t)gr * 64 + c4]);
        xs[row][c4] = v.x; xs[row][c4 + 1] = v.y; xs[row][c4 + 2] = v.z; xs[row][c4 + 3] = v.w;
    }
    // load W2 [64][128]
    for (int l = t; l < 2048; l += 256) {
        int row = l >> 5;
        int c4 = (l & 31) * 4;
        float4 v = *reinterpret_cast<const float4*>(&W[(size_t)row * 128 + c4]);
        ws[row][c4] = v.x; ws[row][c4 + 1] = v.y; ws[row][c4 + 2] = v.z; ws[row][c4 + 3] = v.w;
    }
    __syncthreads();
    float acc[4][8] = {};
#pragma unroll
    for (int k = 0; k < 64; ++k) {
        float a[4], b[8];
#pragma unroll
        for (int i = 0; i < 4; ++i) a[i] = xs[ty * 4 + i][k];
#pragma unroll
        for (int j = 0; j < 8; ++j) b[j] = ws[k][tx * 8 + j];
#pragma unroll
        for (int i = 0; i < 4; ++i)
#pragma unroll
            for (int j = 0; j < 8; ++j) acc[i][j] += a[i] * b[j];
    }
#pragma unroll
    for (int i = 0; i < 4; ++i) {
        int gr = r0 + ty * 4 + i;
        if (gr < Nn) {
#pragma unroll
            for (int j = 0; j < 8; ++j) h2[(size_t)gr * 128 + tx * 8 + j] = acc[i][j];
        }
    }
}

// ---------------- attn coef layer 1: as1/ad1 [N,8] ----------------
__global__ __launch_bounds__(256) void attn1_k(const float* __restrict__ h1,
                                               const float* __restrict__ asrc,
                                               const float* __restrict__ adst,
                                               float* __restrict__ as1,
                                               float* __restrict__ ad1, int Nn) {
    int t = blockIdx.x * 256 + threadIdx.x;
    int n = t >> 3, h = t & 7;
    if (n >= Nn) return;
    const float* hp = h1 + (size_t)n * 64 + h * 8;
    float s = 0.f, d = 0.f;
#pragma unroll
    for (int c = 0; c < 8; ++c) {
        float v = hp[c];
        s += v * asrc[h * 8 + c];
        d += v * adst[h * 8 + c];
    }
    as1[(size_t)n * 8 + h] = s;
    ad1[(size_t)n * 8 + h] = d;
}

// ---------------- attn coef layer 2: as2/ad2 [N] ----------------
__global__ __launch_bounds__(256) void attn2_k(const float* __restrict__ h2,
                                               const float* __restrict__ asrc,
                                               const float* __restrict__ adst,
                                               float* __restrict__ as2,
                                               float* __restrict__ ad2, int Nn) {
    int wid = threadIdx.x >> 6, lane = threadIdx.x & 63;
    int n = blockIdx.x * 4 + wid;
    if (n >= Nn) return;
    float v0 = h2[(size_t)n * 128 + lane];
    float v1 = h2[(size_t)n * 128 + 64 + lane];
    float s = v0 * asrc[lane] + v1 * asrc[64 + lane];
    float d = v0 * adst[lane] + v1 * adst[64 + lane];
#pragma unroll
    for (int off = 32; off >= 1; off >>= 1) {
        s += __shfl_xor(s, off);
        d += __shfl_xor(d, off);
    }
    if (lane == 0) { as2[n] = s; ad2[n] = d; }
}

// ---------------- CSR build ----------------
__global__ __launch_bounds__(256) void hist_k(const int* __restrict__ ei, int E, int Etot,
                                              int* __restrict__ indeg) {
    int e = blockIdx.x * 256 + threadIdx.x;
    if (e >= Etot) return;
    int d = (e < E) ? ei[E + e] : (e - E);
    atomicAdd(&indeg[d], 1);
}

__global__ __launch_bounds__(256) void scanA_k(const int* __restrict__ indeg,
                                               int* __restrict__ indptr,
                                               int* __restrict__ bsums, int Nn) {
    __shared__ int sd[256];
    int t = threadIdx.x;
    int i0 = blockIdx.x * 2048 + t * 8;
    int v[8], ex[8];
    int run = 0;
#pragma unroll
    for (int j = 0; j < 8; ++j) {
        int i = i0 + j;
        v[j] = (i < Nn) ? indeg[i] : 0;
        ex[j] = run;
        run += v[j];
    }
    sd[t] = run;
    __syncthreads();
    for (int off = 1; off < 256; off <<= 1) {
        int a = (t >= off) ? sd[t - off] : 0;
        __syncthreads();
        sd[t] += a;
        __syncthreads();
    }
    int texc = sd[t] - run;
#pragma unroll
    for (int j = 0; j < 8; ++j) {
        int i = i0 + j;
        if (i < Nn) indptr[i] = texc + ex[j];
    }
    if (t == 0) bsums[blockIdx.x] = sd[255];
}

__global__ void scanB_k(int* __restrict__ bsums, int nb) {
    if (threadIdx.x == 0 && blockIdx.x == 0) {
        int run = 0;
        for (int b = 0; b < nb; ++b) {
            int x = bsums[b];
            bsums[b] = run;
            run += x;
        }
    }
}

__global__ __launch_bounds__(256) void scanC_k(int* __restrict__ indptr,
                                               const int* __restrict__ bsums,
                                               int* __restrict__ cursor, int Nn, int Etot) {
    int t = threadIdx.x;
    int b = blockIdx.x;
    int base = bsums[b];
    int i0 = b * 2048 + t * 8;
#pragma unroll
    for (int j = 0; j < 8; ++j) {
        int i = i0 + j;
        if (i < Nn) {
            int val = indptr[i] + base;
            indptr[i] = val;
            cursor[i] = val;
        }
    }
    if (b == 0 && t == 0) indptr[Nn] = Etot;
}

__global__ __launch_bounds__(256) void fill_k(const int* __restrict__ ei, int E, int Etot,
                                              int* __restrict__ cursor, int* __restrict__ col) {
    int e = blockIdx.x * 256 + threadIdx.x;
    if (e >= Etot) return;
    int s, d;
    if (e < E) { s = ei[e]; d = ei[E + e]; }
    else { s = e - E; d = e - E; }
    int pos = atomicAdd(&cursor[d], 1);
    col[pos] = s;
}

// ---------------- aggregation layer 1 (8 heads x 8 ch) + bias + ELU ----------------
__global__ __launch_bounds__(256) void agg1_k(const float* __restrict__ h1,
                                              const float* __restrict__ as1,
                                              const float* __restrict__ ad1,
                                              const int* __restrict__ indptr,
                                              const int* __restrict__ col,
                                              const float* __restrict__ b1,
                                              float* __restrict__ h1a, int Nn) {
    int wid = threadIdx.x >> 6, lane = threadIdx.x & 63;
    int n = blockIdx.x * 4 + wid;
    if (n >= Nn) return;
    int beg = indptr[n], end = indptr[n + 1];
    int h = lane & 7, eo = lane >> 3;
    float adn = ad1[(size_t)n * 8 + h];
    float m = -1e30f;
    for (int i = beg + eo; i < end; i += 8) {
        int s = col[i];
        float v = lrelu(as1[(size_t)s * 8 + h] + adn);
        m = fmaxf(m, v);
    }
    m = fmaxf(m, __shfl_xor(m, 8));
    m = fmaxf(m, __shfl_xor(m, 16));
    m = fmaxf(m, __shfl_xor(m, 32));
    float ss = 0.f;
    for (int i = beg + eo; i < end; i += 8) {
        int s = col[i];
        float v = lrelu(as1[(size_t)s * 8 + h] + adn);
        ss += expf(v - m);
    }
    ss += __shfl_xor(ss, 8);
    ss += __shfl_xor(ss, 16);
    ss += __shfl_xor(ss, 32);
    // redistribute to phase-B layout: lane handles channel lane = hb*8 + c
    int hb = lane >> 3;
    float mb = __shfl(m, hb);
    float sb = __shfl(ss, hb);
    float ab = __shfl(adn, hb);
    float inv = 1.f / sb;
    float acc = 0.f;
    for (int i = beg; i < end; ++i) {
        int s = col[i];
        float v = lrelu(as1[(size_t)s * 8 + hb] + ab);
        float wgt = expf(v - mb) * inv;
        acc += wgt * h1[(size_t)s * 64 + lane];
    }
    float o = acc + b1[lane];
    h1a[(size_t)n * 64 + lane] = o > 0.f ? o : expm1f(o);
}

// ---------------- aggregation layer 2 (1 head x 128 ch) + bias ----------------
__global__ __launch_bounds__(256) void agg2_k(const float* __restrict__ h2,
                                              const float* __restrict__ as2,
                                              const float* __restrict__ ad2,
                                              const int* __restrict__ indptr,
                                              const int* __restrict__ col,
                                              const float* __restrict__ b2,
                                              float* __restrict__ out, int Nn) {
    int wid = threadIdx.x >> 6, lane = threadIdx.x & 63;
    int n = blockIdx.x * 4 + wid;
    if (n >= Nn) return;
    int beg = indptr[n], end = indptr[n + 1];
    float adn = ad2[n];
    float m = -1e30f;
    for (int i = beg + lane; i < end; i += 64) {
        int s = col[i];
        m = fmaxf(m, lrelu(as2[s] + adn));
    }
#pragma unroll
    for (int off = 32; off >= 1; off >>= 1) m = fmaxf(m, __shfl_xor(m, off));
    float ss = 0.f;
    for (int i = beg + lane; i < end; i += 64) {
        int s = col[i];
        ss += expf(lrelu(as2[s] + adn) - m);
    }
#pragma unroll
    for (int off = 32; off >= 1; off >>= 1) ss += __shfl_xor(ss, off);
    float inv = 1.f / ss;
    float a0 = 0.f, a1 = 0.f;
    for (int i = beg; i < end; ++i) {
        int s = col[i];
        float wgt = expf(lrelu(as2[s] + adn) - m) * inv;
        a0 += wgt * h2[(size_t)s * 128 + lane];
        a1 += wgt * h2[(size_t)s * 128 + 64 + lane];
    }
    out[(size_t)n * 128 + lane] = a0 + b2[lane];
    out[(size_t)n * 128 + 64 + lane] = a1 + b2[64 + lane];
}

extern "C" void kernel_launch(void* const* d_in, const int* in_sizes, int n_in,
                              void* d_out, int out_size, void* d_ws, size_t ws_size,
                              hipStream_t stream) {
    const float* x = (const float*)d_in[0];
    const int* ei = (const int*)d_in[1];
    const float* W1 = (const float*)d_in[2];
    const float* asrc1 = (const float*)d_in[3];
    const float* adst1 = (const float*)d_in[4];
    const float* b1 = (const float*)d_in[5];
    const float* W2 = (const float*)d_in[6];
    const float* asrc2 = (const float*)d_in[7];
    const float* adst2 = (const float*)d_in[8];
    const float* b2 = (const float*)d_in[9];
    float* out = (float*)d_out;

    const int Nn = NNODES;
    const int E = in_sizes[1] / 2;
    const int Etot = E + Nn;

    char* w = (char*)d_ws;
    auto alloc = [&](size_t bytes) {
        char* p = w;
        w += (bytes + 255) & ~(size_t)255;
        return p;
    };
    float* h1 = (float*)alloc((size_t)Nn * 64 * 4);
    float* h1a = (float*)alloc((size_t)Nn * 64 * 4);
    float* h2 = (float*)alloc((size_t)Nn * 128 * 4);
    float* as1 = (float*)alloc((size_t)Nn * 8 * 4);
    float* ad1 = (float*)alloc((size_t)Nn * 8 * 4);
    float* as2 = (float*)alloc((size_t)Nn * 4);
    float* ad2 = (float*)alloc((size_t)Nn * 4);
    int* indeg = (int*)alloc((size_t)(Nn + 1) * 4);
    int* indptr = (int*)alloc((size_t)(Nn + 1) * 4);
    int* cursor = (int*)alloc((size_t)Nn * 4);
    int* bsums = (int*)alloc(4096);
    int* col = (int*)alloc((size_t)Etot * 4);

    const int NBLK = (Nn + 2047) / 2048;

    hipMemsetAsync(indeg, 0, (size_t)Nn * 4, stream);
    gemm1_k<<<(Nn + 63) / 64, 256, 0, stream>>>(x, W1, h1, Nn);
    attn1_k<<<(Nn * 8 + 255) / 256, 256, 0, stream>>>(h1, asrc1, adst1, as1, ad1, Nn);
    hist_k<<<(Etot + 255) / 256, 256, 0, stream>>>(ei, E, Etot, indeg);
    scanA_k<<<NBLK, 256, 0, stream>>>(indeg, indptr, bsums, Nn);
    scanB_k<<<1, 64, 0, stream>>>(bsums, NBLK);
    scanC_k<<<NBLK, 256, 0, stream>>>(indptr, bsums, cursor, Nn, Etot);
    fill_k<<<(Etot + 255) / 256, 256, 0, stream>>>(ei, E, Etot, cursor, col);
    agg1_k<<<(Nn + 3) / 4, 256, 0, stream>>>(h1, as1, ad1, indptr, col, b1, h1a, Nn);
    gemm2_k<<<(Nn + 63) / 64, 256, 0, stream>>>(h1a, W2, h2, Nn);
    attn2_k<<<(Nn + 3) / 4, 256, 0, stream>>>(h2, asrc2, adst2, as2, ad2, Nn);
    agg2_k<<<(Nn + 3) / 4, 256, 0, stream>>>(h2, as2, ad2, indptr, col, b2, out, Nn);
}

// Round 3
// 1071.701 us; speedup vs baseline: 1.6174x; 1.6174x over previous
//
#include <hip/hip_runtime.h>
#include <math.h>

#define NNODES 100000

__device__ __forceinline__ float lrelu(float v) { return v > 0.f ? v : 0.2f * v; }

// ---------------- GEMM1: h1[N,64] = x[N,512] @ W1[512,64] ----------------
__global__ __launch_bounds__(256) void gemm1_k(const float* __restrict__ x,
                                               const float* __restrict__ W,
                                               float* __restrict__ h1, int Nn) {
    __shared__ float xs[64][65];
    __shared__ float ws[64][65];
    int r0 = blockIdx.x * 64;
    int t = threadIdx.x;
    int ty = t >> 4, tx = t & 15;
    float acc[4][4] = {};
    for (int kb = 0; kb < 512; kb += 64) {
        for (int l = t; l < 1024; l += 256) {
            int row = l >> 4;
            int c4 = (l & 15) * 4;
            int gr = r0 + row;
            float4 v = make_float4(0.f, 0.f, 0.f, 0.f);
            if (gr < Nn) v = *reinterpret_cast<const float4*>(&x[(size_t)gr * 512 + kb + c4]);
            xs[row][c4] = v.x; xs[row][c4 + 1] = v.y; xs[row][c4 + 2] = v.z; xs[row][c4 + 3] = v.w;
        }
        for (int l = t; l < 1024; l += 256) {
            int row = l >> 4;
            int c4 = (l & 15) * 4;
            float4 v = *reinterpret_cast<const float4*>(&W[(size_t)(kb + row) * 64 + c4]);
            ws[row][c4] = v.x; ws[row][c4 + 1] = v.y; ws[row][c4 + 2] = v.z; ws[row][c4 + 3] = v.w;
        }
        __syncthreads();
#pragma unroll 8
        for (int k = 0; k < 64; ++k) {
            float a[4], b[4];
#pragma unroll
            for (int i = 0; i < 4; ++i) a[i] = xs[ty * 4 + i][k];
#pragma unroll
            for (int j = 0; j < 4; ++j) b[j] = ws[k][tx * 4 + j];
#pragma unroll
            for (int i = 0; i < 4; ++i)
#pragma unroll
                for (int j = 0; j < 4; ++j) acc[i][j] += a[i] * b[j];
        }
        __syncthreads();
    }
#pragma unroll
    for (int i = 0; i < 4; ++i) {
        int gr = r0 + ty * 4 + i;
        if (gr < Nn) {
#pragma unroll
            for (int j = 0; j < 4; ++j) h1[(size_t)gr * 64 + tx * 4 + j] = acc[i][j];
        }
    }
}

// ---------------- GEMM2: h2[N,128] = h1a[N,64] @ W2[64,128] ----------------
// per-thread columns: {tx*4 .. tx*4+3} and {64+tx*4 .. 64+tx*4+3}  (stride-16B
// LDS reads -> conflict-free)
__global__ __launch_bounds__(256) void gemm2_k(const float* __restrict__ xin,
                                               const float* __restrict__ W,
                                               float* __restrict__ h2, int Nn) {
    __shared__ float xs[64][65];
    __shared__ float ws[64][129];
    int r0 = blockIdx.x * 64;
    int t = threadIdx.x;
    int ty = t >> 4, tx = t & 15;
    // load x tile [64][64]
    for (int l = t; l < 1024; l += 256) {
        int row = l >> 4;
        int c4 = (l & 15) * 4;
        int gr = r0 + row;
        float4 v = make_float4(0.f, 0.f, 0.f, 0.f);
        if (gr < Nn) v = *reinterpret_cast<const float4*>(&xin[(size_t)gr * 64 + c4]);
        xs[row][c4] = v.x; xs[row][c4 + 1] = v.y; xs[row][c4 + 2] = v.z; xs[row][c4 + 3] = v.w;
    }
    // load W2 [64][128]
    for (int l = t; l < 2048; l += 256) {
        int row = l >> 5;
        int c4 = (l & 31) * 4;
        float4 v = *reinterpret_cast<const float4*>(&W[(size_t)row * 128 + c4]);
        ws[row][c4] = v.x; ws[row][c4 + 1] = v.y; ws[row][c4 + 2] = v.z; ws[row][c4 + 3] = v.w;
    }
    __syncthreads();
    float acc0[4][4] = {};
    float acc1[4][4] = {};
#pragma unroll 8
    for (int k = 0; k < 64; ++k) {
        float a[4], b0[4], b1[4];
#pragma unroll
        for (int i = 0; i < 4; ++i) a[i] = xs[ty * 4 + i][k];
#pragma unroll
        for (int j = 0; j < 4; ++j) { b0[j] = ws[k][tx * 4 + j]; b1[j] = ws[k][64 + tx * 4 + j]; }
#pragma unroll
        for (int i = 0; i < 4; ++i)
#pragma unroll
            for (int j = 0; j < 4; ++j) {
                acc0[i][j] += a[i] * b0[j];
                acc1[i][j] += a[i] * b1[j];
            }
    }
#pragma unroll
    for (int i = 0; i < 4; ++i) {
        int gr = r0 + ty * 4 + i;
        if (gr < Nn) {
#pragma unroll
            for (int j = 0; j < 4; ++j) {
                h2[(size_t)gr * 128 + tx * 4 + j] = acc0[i][j];
                h2[(size_t)gr * 128 + 64 + tx * 4 + j] = acc1[i][j];
            }
        }
    }
}

// ---------------- attn coef layer 1: as1/ad1 [N,8] ----------------
__global__ __launch_bounds__(256) void attn1_k(const float* __restrict__ h1,
                                               const float* __restrict__ asrc,
                                               const float* __restrict__ adst,
                                               float* __restrict__ as1,
                                               float* __restrict__ ad1, int Nn) {
    int t = blockIdx.x * 256 + threadIdx.x;
    int n = t >> 3, h = t & 7;
    if (n >= Nn) return;
    const float* hp = h1 + (size_t)n * 64 + h * 8;
    float s = 0.f, d = 0.f;
#pragma unroll
    for (int c = 0; c < 8; ++c) {
        float v = hp[c];
        s += v * asrc[h * 8 + c];
        d += v * adst[h * 8 + c];
    }
    as1[(size_t)n * 8 + h] = s;
    ad1[(size_t)n * 8 + h] = d;
}

// ---------------- attn coef layer 2: as2/ad2 [N] ----------------
__global__ __launch_bounds__(256) void attn2_k(const float* __restrict__ h2,
                                               const float* __restrict__ asrc,
                                               const float* __restrict__ adst,
                                               float* __restrict__ as2,
                                               float* __restrict__ ad2, int Nn) {
    int wid = threadIdx.x >> 6, lane = threadIdx.x & 63;
    int n = blockIdx.x * 4 + wid;
    if (n >= Nn) return;
    float v0 = h2[(size_t)n * 128 + lane];
    float v1 = h2[(size_t)n * 128 + 64 + lane];
    float s = v0 * asrc[lane] + v1 * asrc[64 + lane];
    float d = v0 * adst[lane] + v1 * adst[64 + lane];
#pragma unroll
    for (int off = 32; off >= 1; off >>= 1) {
        s += __shfl_xor(s, off);
        d += __shfl_xor(d, off);
    }
    if (lane == 0) { as2[n] = s; ad2[n] = d; }
}

// ---------------- CSR build ----------------
__global__ __launch_bounds__(256) void hist_k(const int* __restrict__ ei, int E, int Etot,
                                              int* __restrict__ indeg) {
    int e = blockIdx.x * 256 + threadIdx.x;
    if (e >= Etot) return;
    int d = (e < E) ? ei[E + e] : (e - E);
    atomicAdd(&indeg[d], 1);
}

__global__ __launch_bounds__(256) void scanA_k(const int* __restrict__ indeg,
                                               int* __restrict__ indptr,
                                               int* __restrict__ bsums, int Nn) {
    __shared__ int sd[256];
    int t = threadIdx.x;
    int i0 = blockIdx.x * 2048 + t * 8;
    int v[8], ex[8];
    int run = 0;
#pragma unroll
    for (int j = 0; j < 8; ++j) {
        int i = i0 + j;
        v[j] = (i < Nn) ? indeg[i] : 0;
        ex[j] = run;
        run += v[j];
    }
    sd[t] = run;
    __syncthreads();
    for (int off = 1; off < 256; off <<= 1) {
        int a = (t >= off) ? sd[t - off] : 0;
        __syncthreads();
        sd[t] += a;
        __syncthreads();
    }
    int texc = sd[t] - run;
#pragma unroll
    for (int j = 0; j < 8; ++j) {
        int i = i0 + j;
        if (i < Nn) indptr[i] = texc + ex[j];
    }
    if (t == 0) bsums[blockIdx.x] = sd[255];
}

__global__ void scanB_k(int* __restrict__ bsums, int nb) {
    if (threadIdx.x == 0 && blockIdx.x == 0) {
        int run = 0;
        for (int b = 0; b < nb; ++b) {
            int x = bsums[b];
            bsums[b] = run;
            run += x;
        }
    }
}

__global__ __launch_bounds__(256) void scanC_k(int* __restrict__ indptr,
                                               const int* __restrict__ bsums,
                                               int* __restrict__ cursor, int Nn, int Etot) {
    int t = threadIdx.x;
    int b = blockIdx.x;
    int base = bsums[b];
    int i0 = b * 2048 + t * 8;
#pragma unroll
    for (int j = 0; j < 8; ++j) {
        int i = i0 + j;
        if (i < Nn) {
            int val = indptr[i] + base;
            indptr[i] = val;
            cursor[i] = val;
        }
    }
    if (b == 0 && t == 0) indptr[Nn] = Etot;
}

__global__ __launch_bounds__(256) void fill_k(const int* __restrict__ ei, int E, int Etot,
                                              int* __restrict__ cursor, int* __restrict__ col) {
    int e = blockIdx.x * 256 + threadIdx.x;
    if (e >= Etot) return;
    int s, d;
    if (e < E) { s = ei[e]; d = ei[E + e]; }
    else { s = e - E; d = e - E; }
    int pos = atomicAdd(&cursor[d], 1);
    col[pos] = s;
}

// ---------------- aggregation layer 1 (8 heads x 8 ch) + bias + ELU ----------------
__global__ __launch_bounds__(256) void agg1_k(const float* __restrict__ h1,
                                              const float* __restrict__ as1,
                                              const float* __restrict__ ad1,
                                              const int* __restrict__ indptr,
                                              const int* __restrict__ col,
                                              const float* __restrict__ b1,
                                              float* __restrict__ h1a, int Nn) {
    int wid = threadIdx.x >> 6, lane = threadIdx.x & 63;
    int n = blockIdx.x * 4 + wid;
    if (n >= Nn) return;
    int beg = indptr[n], end = indptr[n + 1];
    int h = lane & 7, eo = lane >> 3;
    float adn = ad1[(size_t)n * 8 + h];
    float m = -1e30f;
    for (int i = beg + eo; i < end; i += 8) {
        int s = col[i];
        float v = lrelu(as1[(size_t)s * 8 + h] + adn);
        m = fmaxf(m, v);
    }
    m = fmaxf(m, __shfl_xor(m, 8));
    m = fmaxf(m, __shfl_xor(m, 16));
    m = fmaxf(m, __shfl_xor(m, 32));
    float ss = 0.f;
    for (int i = beg + eo; i < end; i += 8) {
        int s = col[i];
        float v = lrelu(as1[(size_t)s * 8 + h] + adn);
        ss += expf(v - m);
    }
    ss += __shfl_xor(ss, 8);
    ss += __shfl_xor(ss, 16);
    ss += __shfl_xor(ss, 32);
    // redistribute to phase-B layout: lane handles channel lane = hb*8 + c
    int hb = lane >> 3;
    float mb = __shfl(m, hb);
    float sb = __shfl(ss, hb);
    float ab = __shfl(adn, hb);
    float inv = 1.f / sb;
    float acc = 0.f;
    for (int i = beg; i < end; ++i) {
        int s = col[i];
        float v = lrelu(as1[(size_t)s * 8 + hb] + ab);
        float wgt = expf(v - mb) * inv;
        acc += wgt * h1[(size_t)s * 64 + lane];
    }
    float o = acc + b1[lane];
    h1a[(size_t)n * 64 + lane] = o > 0.f ? o : expm1f(o);
}

// ---------------- aggregation layer 2 (1 head x 128 ch) + bias ----------------
__global__ __launch_bounds__(256) void agg2_k(const float* __restrict__ h2,
                                              const float* __restrict__ as2,
                                              const float* __restrict__ ad2,
                                              const int* __restrict__ indptr,
                                              const int* __restrict__ col,
                                              const float* __restrict__ b2,
                                              float* __restrict__ out, int Nn) {
    int wid = threadIdx.x >> 6, lane = threadIdx.x & 63;
    int n = blockIdx.x * 4 + wid;
    if (n >= Nn) return;
    int beg = indptr[n], end = indptr[n + 1];
    float adn = ad2[n];
    float m = -1e30f;
    for (int i = beg + lane; i < end; i += 64) {
        int s = col[i];
        m = fmaxf(m, lrelu(as2[s] + adn));
    }
#pragma unroll
    for (int off = 32; off >= 1; off >>= 1) m = fmaxf(m, __shfl_xor(m, off));
    float ss = 0.f;
    for (int i = beg + lane; i < end; i += 64) {
        int s = col[i];
        ss += expf(lrelu(as2[s] + adn) - m);
    }
#pragma unroll
    for (int off = 32; off >= 1; off >>= 1) ss += __shfl_xor(ss, off);
    float inv = 1.f / ss;
    float a0 = 0.f, a1 = 0.f;
    for (int i = beg; i < end; ++i) {
        int s = col[i];
        float wgt = expf(lrelu(as2[s] + adn) - m) * inv;
        a0 += wgt * h2[(size_t)s * 128 + lane];
        a1 += wgt * h2[(size_t)s * 128 + 64 + lane];
    }
    out[(size_t)n * 128 + lane] = a0 + b2[lane];
    out[(size_t)n * 128 + 64 + lane] = a1 + b2[64 + lane];
}

extern "C" void kernel_launch(void* const* d_in, const int* in_sizes, int n_in,
                              void* d_out, int out_size, void* d_ws, size_t ws_size,
                              hipStream_t stream) {
    const float* x = (const float*)d_in[0];
    const int* ei = (const int*)d_in[1];
    const float* W1 = (const float*)d_in[2];
    const float* asrc1 = (const float*)d_in[3];
    const float* adst1 = (const float*)d_in[4];
    const float* b1 = (const float*)d_in[5];
    const float* W2 = (const float*)d_in[6];
    const float* asrc2 = (const float*)d_in[7];
    const float* adst2 = (const float*)d_in[8];
    const float* b2 = (const float*)d_in[9];
    float* out = (float*)d_out;

    const int Nn = NNODES;
    const int E = in_sizes[1] / 2;
    const int Etot = E + Nn;

    char* w = (char*)d_ws;
    auto alloc = [&](size_t bytes) {
        char* p = w;
        w += (bytes + 255) & ~(size_t)255;
        return p;
    };
    float* h1 = (float*)alloc((size_t)Nn * 64 * 4);
    float* h1a = (float*)alloc((size_t)Nn * 64 * 4);
    float* h2 = (float*)alloc((size_t)Nn * 128 * 4);
    float* as1 = (float*)alloc((size_t)Nn * 8 * 4);
    float* ad1 = (float*)alloc((size_t)Nn * 8 * 4);
    float* as2 = (float*)alloc((size_t)Nn * 4);
    float* ad2 = (float*)alloc((size_t)Nn * 4);
    int* indeg = (int*)alloc((size_t)(Nn + 1) * 4);
    int* indptr = (int*)alloc((size_t)(Nn + 1) * 4);
    int* cursor = (int*)alloc((size_t)Nn * 4);
    int* bsums = (int*)alloc(4096);
    int* col = (int*)alloc((size_t)Etot * 4);

    const int NBLK = (Nn + 2047) / 2048;

    hipMemsetAsync(indeg, 0, (size_t)Nn * 4, stream);
    gemm1_k<<<(Nn + 63) / 64, 256, 0, stream>>>(x, W1, h1, Nn);
    attn1_k<<<(Nn * 8 + 255) / 256, 256, 0, stream>>>(h1, asrc1, adst1, as1, ad1, Nn);
    hist_k<<<(Etot + 255) / 256, 256, 0, stream>>>(ei, E, Etot, indeg);
    scanA_k<<<NBLK, 256, 0, stream>>>(indeg, indptr, bsums, Nn);
    scanB_k<<<1, 64, 0, stream>>>(bsums, NBLK);
    scanC_k<<<NBLK, 256, 0, stream>>>(indptr, bsums, cursor, Nn, Etot);
    fill_k<<<(Etot + 255) / 256, 256, 0, stream>>>(ei, E, Etot, cursor, col);
    agg1_k<<<(Nn + 3) / 4, 256, 0, stream>>>(h1, as1, ad1, indptr, col, b1, h1a, Nn);
    gemm2_k<<<(Nn + 63) / 64, 256, 0, stream>>>(h1a, W2, h2, Nn);
    attn2_k<<<(Nn + 3) / 4, 256, 0, stream>>>(h2, asrc2, adst2, as2, ad2, Nn);
    agg2_k<<<(Nn + 3) / 4, 256, 0, stream>>>(h2, as2, ad2, indptr, col, b2, out, Nn);
}

// Round 4
// 902.141 us; speedup vs baseline: 1.9214x; 1.1880x over previous
//
#include <hip/hip_runtime.h>
#include <math.h>

#define NNODES 100000

__device__ __forceinline__ float lrelu(float v) { return v > 0.f ? v : 0.2f * v; }

// ---------------- GEMM1: h1[N,64] = x[N,512] @ W1[512,64] ----------------
__global__ __launch_bounds__(256) void gemm1_k(const float* __restrict__ x,
                                               const float* __restrict__ W,
                                               float* __restrict__ h1, int Nn) {
    __shared__ float xs[64][65];
    __shared__ float ws[64][65];
    int r0 = blockIdx.x * 64;
    int t = threadIdx.x;
    int ty = t >> 4, tx = t & 15;
    float acc[4][4] = {};
    for (int kb = 0; kb < 512; kb += 64) {
        for (int l = t; l < 1024; l += 256) {
            int row = l >> 4;
            int c4 = (l & 15) * 4;
            int gr = r0 + row;
            float4 v = make_float4(0.f, 0.f, 0.f, 0.f);
            if (gr < Nn) v = *reinterpret_cast<const float4*>(&x[(size_t)gr * 512 + kb + c4]);
            xs[row][c4] = v.x; xs[row][c4 + 1] = v.y; xs[row][c4 + 2] = v.z; xs[row][c4 + 3] = v.w;
        }
        for (int l = t; l < 1024; l += 256) {
            int row = l >> 4;
            int c4 = (l & 15) * 4;
            float4 v = *reinterpret_cast<const float4*>(&W[(size_t)(kb + row) * 64 + c4]);
            ws[row][c4] = v.x; ws[row][c4 + 1] = v.y; ws[row][c4 + 2] = v.z; ws[row][c4 + 3] = v.w;
        }
        __syncthreads();
#pragma unroll 8
        for (int k = 0; k < 64; ++k) {
            float a[4], b[4];
#pragma unroll
            for (int i = 0; i < 4; ++i) a[i] = xs[ty * 4 + i][k];
#pragma unroll
            for (int j = 0; j < 4; ++j) b[j] = ws[k][tx * 4 + j];
#pragma unroll
            for (int i = 0; i < 4; ++i)
#pragma unroll
                for (int j = 0; j < 4; ++j) acc[i][j] += a[i] * b[j];
        }
        __syncthreads();
    }
#pragma unroll
    for (int i = 0; i < 4; ++i) {
        int gr = r0 + ty * 4 + i;
        if (gr < Nn) {
#pragma unroll
            for (int j = 0; j < 4; ++j) h1[(size_t)gr * 64 + tx * 4 + j] = acc[i][j];
        }
    }
}

// ---------------- GEMM2: h2[N,128] = h1a[N,64] @ W2[64,128] ----------------
__global__ __launch_bounds__(256) void gemm2_k(const float* __restrict__ xin,
                                               const float* __restrict__ W,
                                               float* __restrict__ h2, int Nn) {
    __shared__ float xs[64][65];
    __shared__ float ws[64][129];
    int r0 = blockIdx.x * 64;
    int t = threadIdx.x;
    int ty = t >> 4, tx = t & 15;
    for (int l = t; l < 1024; l += 256) {
        int row = l >> 4;
        int c4 = (l & 15) * 4;
        int gr = r0 + row;
        float4 v = make_float4(0.f, 0.f, 0.f, 0.f);
        if (gr < Nn) v = *reinterpret_cast<const float4*>(&xin[(size_t)gr * 64 + c4]);
        xs[row][c4] = v.x; xs[row][c4 + 1] = v.y; xs[row][c4 + 2] = v.z; xs[row][c4 + 3] = v.w;
    }
    for (int l = t; l < 2048; l += 256) {
        int row = l >> 5;
        int c4 = (l & 31) * 4;
        float4 v = *reinterpret_cast<const float4*>(&W[(size_t)row * 128 + c4]);
        ws[row][c4] = v.x; ws[row][c4 + 1] = v.y; ws[row][c4 + 2] = v.z; ws[row][c4 + 3] = v.w;
    }
    __syncthreads();
    float acc0[4][4] = {};
    float acc1[4][4] = {};
#pragma unroll 8
    for (int k = 0; k < 64; ++k) {
        float a[4], b0[4], b1[4];
#pragma unroll
        for (int i = 0; i < 4; ++i) a[i] = xs[ty * 4 + i][k];
#pragma unroll
        for (int j = 0; j < 4; ++j) { b0[j] = ws[k][tx * 4 + j]; b1[j] = ws[k][64 + tx * 4 + j]; }
#pragma unroll
        for (int i = 0; i < 4; ++i)
#pragma unroll
            for (int j = 0; j < 4; ++j) {
                acc0[i][j] += a[i] * b0[j];
                acc1[i][j] += a[i] * b1[j];
            }
    }
#pragma unroll
    for (int i = 0; i < 4; ++i) {
        int gr = r0 + ty * 4 + i;
        if (gr < Nn) {
#pragma unroll
            for (int j = 0; j < 4; ++j) {
                h2[(size_t)gr * 128 + tx * 4 + j] = acc0[i][j];
                h2[(size_t)gr * 128 + 64 + tx * 4 + j] = acc1[i][j];
            }
        }
    }
}

// ---------------- attn coef layer 1: as1/ad1 [N,8] ----------------
__global__ __launch_bounds__(256) void attn1_k(const float* __restrict__ h1,
                                               const float* __restrict__ asrc,
                                               const float* __restrict__ adst,
                                               float* __restrict__ as1,
                                               float* __restrict__ ad1, int Nn) {
    int t = blockIdx.x * 256 + threadIdx.x;
    int n = t >> 3, h = t & 7;
    if (n >= Nn) return;
    const float* hp = h1 + (size_t)n * 64 + h * 8;
    float s = 0.f, d = 0.f;
#pragma unroll
    for (int c = 0; c < 8; ++c) {
        float v = hp[c];
        s += v * asrc[h * 8 + c];
        d += v * adst[h * 8 + c];
    }
    as1[(size_t)n * 8 + h] = s;
    ad1[(size_t)n * 8 + h] = d;
}

// ---------------- attn coef layer 2: as2/ad2 [N] ----------------
__global__ __launch_bounds__(256) void attn2_k(const float* __restrict__ h2,
                                               const float* __restrict__ asrc,
                                               const float* __restrict__ adst,
                                               float* __restrict__ as2,
                                               float* __restrict__ ad2, int Nn) {
    int wid = threadIdx.x >> 6, lane = threadIdx.x & 63;
    int n = blockIdx.x * 4 + wid;
    if (n >= Nn) return;
    float v0 = h2[(size_t)n * 128 + lane];
    float v1 = h2[(size_t)n * 128 + 64 + lane];
    float s = v0 * asrc[lane] + v1 * asrc[64 + lane];
    float d = v0 * adst[lane] + v1 * adst[64 + lane];
#pragma unroll
    for (int off = 32; off >= 1; off >>= 1) {
        s += __shfl_xor(s, off);
        d += __shfl_xor(d, off);
    }
    if (lane == 0) { as2[n] = s; ad2[n] = d; }
}

// ---------------- CSR build ----------------
__global__ __launch_bounds__(256) void hist_k(const int* __restrict__ ei, int E, int Etot,
                                              int* __restrict__ indeg) {
    int e = blockIdx.x * 256 + threadIdx.x;
    if (e >= Etot) return;
    int d = (e < E) ? ei[E + e] : (e - E);
    atomicAdd(&indeg[d], 1);
}

__global__ __launch_bounds__(256) void scanA_k(const int* __restrict__ indeg,
                                               int* __restrict__ indptr,
                                               int* __restrict__ bsums, int Nn) {
    __shared__ int sd[256];
    int t = threadIdx.x;
    int i0 = blockIdx.x * 2048 + t * 8;
    int v[8], ex[8];
    int run = 0;
#pragma unroll
    for (int j = 0; j < 8; ++j) {
        int i = i0 + j;
        v[j] = (i < Nn) ? indeg[i] : 0;
        ex[j] = run;
        run += v[j];
    }
    sd[t] = run;
    __syncthreads();
    for (int off = 1; off < 256; off <<= 1) {
        int a = (t >= off) ? sd[t - off] : 0;
        __syncthreads();
        sd[t] += a;
        __syncthreads();
    }
    int texc = sd[t] - run;
#pragma unroll
    for (int j = 0; j < 8; ++j) {
        int i = i0 + j;
        if (i < Nn) indptr[i] = texc + ex[j];
    }
    if (t == 0) bsums[blockIdx.x] = sd[255];
}

__global__ void scanB_k(int* __restrict__ bsums, int nb) {
    if (threadIdx.x == 0 && blockIdx.x == 0) {
        int run = 0;
        for (int b = 0; b < nb; ++b) {
            int x = bsums[b];
            bsums[b] = run;
            run += x;
        }
    }
}

__global__ __launch_bounds__(256) void scanC_k(int* __restrict__ indptr,
                                               const int* __restrict__ bsums,
                                               int* __restrict__ cursor, int Nn, int Etot) {
    int t = threadIdx.x;
    int b = blockIdx.x;
    int base = bsums[b];
    int i0 = b * 2048 + t * 8;
#pragma unroll
    for (int j = 0; j < 8; ++j) {
        int i = i0 + j;
        if (i < Nn) {
            int val = indptr[i] + base;
            indptr[i] = val;
            cursor[i] = val;
        }
    }
    if (b == 0 && t == 0) indptr[Nn] = Etot;
}

__global__ __launch_bounds__(256) void fill_k(const int* __restrict__ ei, int E, int Etot,
                                              int* __restrict__ cursor, int* __restrict__ col) {
    int e = blockIdx.x * 256 + threadIdx.x;
    if (e >= Etot) return;
    int s, d;
    if (e < E) { s = ei[e]; d = ei[E + e]; }
    else { s = e - E; d = e - E; }
    int pos = atomicAdd(&cursor[d], 1);
    col[pos] = s;
}

// ---------------- aggregation layer 1 (8 heads x 8 ch) + bias + ELU ----------------
// no-max softmax (|e| small -> exp safe in fp32); phase B unrolled 4x for MLP
__global__ __launch_bounds__(256) void agg1_k(const float* __restrict__ h1,
                                              const float* __restrict__ as1,
                                              const float* __restrict__ ad1,
                                              const int* __restrict__ indptr,
                                              const int* __restrict__ col,
                                              const float* __restrict__ b1,
                                              float* __restrict__ h1a, int Nn) {
    int wid = threadIdx.x >> 6, lane = threadIdx.x & 63;
    int n = blockIdx.x * 4 + wid;
    if (n >= Nn) return;
    int beg = indptr[n], end = indptr[n + 1];
    int h = lane & 7, eo = lane >> 3;
    float adn = ad1[(size_t)n * 8 + h];
    // denominator pass: 8 lane-groups x 8 heads, 8 edges per wave-iter
    float ss = 0.f;
    for (int i = beg + eo; i < end; i += 8) {
        int s = col[i];
        ss += __expf(lrelu(as1[(size_t)s * 8 + h] + adn));
    }
    ss += __shfl_xor(ss, 8);
    ss += __shfl_xor(ss, 16);
    ss += __shfl_xor(ss, 32);
    // phase B: lane owns channel `lane` = hb*8 + c; head-hb scalars live in lane hb
    int hb = lane >> 3;
    float sb = __shfl(ss, hb);
    float ab = __shfl(adn, hb);
    float inv = 1.f / sb;
    const float* __restrict__ h1l = h1 + lane;
    float acc0 = 0.f, acc1 = 0.f, acc2 = 0.f, acc3 = 0.f;
    int i = beg;
    for (; i + 4 <= end; i += 4) {
        int s0 = col[i], s1 = col[i + 1], s2 = col[i + 2], s3 = col[i + 3];
        float w0 = __expf(lrelu(as1[(size_t)s0 * 8 + hb] + ab));
        float w1 = __expf(lrelu(as1[(size_t)s1 * 8 + hb] + ab));
        float w2 = __expf(lrelu(as1[(size_t)s2 * 8 + hb] + ab));
        float w3 = __expf(lrelu(as1[(size_t)s3 * 8 + hb] + ab));
        acc0 += w0 * h1l[(size_t)s0 * 64];
        acc1 += w1 * h1l[(size_t)s1 * 64];
        acc2 += w2 * h1l[(size_t)s2 * 64];
        acc3 += w3 * h1l[(size_t)s3 * 64];
    }
    for (; i < end; ++i) {
        int s = col[i];
        acc0 += __expf(lrelu(as1[(size_t)s * 8 + hb] + ab)) * h1l[(size_t)s * 64];
    }
    float o = ((acc0 + acc1) + (acc2 + acc3)) * inv + b1[lane];
    h1a[(size_t)n * 64 + lane] = o > 0.f ? o : expm1f(o);
}

// ---------------- aggregation layer 2 (1 head x 128 ch) + bias ----------------
__global__ __launch_bounds__(256) void agg2_k(const float* __restrict__ h2,
                                              const float* __restrict__ as2,
                                              const float* __restrict__ ad2,
                                              const int* __restrict__ indptr,
                                              const int* __restrict__ col,
                                              const float* __restrict__ b2,
                                              float* __restrict__ out, int Nn) {
    int wid = threadIdx.x >> 6, lane = threadIdx.x & 63;
    int n = blockIdx.x * 4 + wid;
    if (n >= Nn) return;
    int beg = indptr[n], end = indptr[n + 1];
    float adn = ad2[n];
    // denominator pass: 64 edges per wave-iter
    float ss = 0.f;
    for (int i = beg + lane; i < end; i += 64) {
        ss += __expf(lrelu(as2[col[i]] + adn));
    }
#pragma unroll
    for (int off = 32; off >= 1; off >>= 1) ss += __shfl_xor(ss, off);
    float inv = 1.f / ss;
    const float* __restrict__ h2l = h2 + lane;
    float a00 = 0.f, a01 = 0.f, a02 = 0.f, a03 = 0.f;
    float a10 = 0.f, a11 = 0.f, a12 = 0.f, a13 = 0.f;
    int i = beg;
    for (; i + 4 <= end; i += 4) {
        int s0 = col[i], s1 = col[i + 1], s2 = col[i + 2], s3 = col[i + 3];
        float w0 = __expf(lrelu(as2[s0] + adn));
        float w1 = __expf(lrelu(as2[s1] + adn));
        float w2 = __expf(lrelu(as2[s2] + adn));
        float w3 = __expf(lrelu(as2[s3] + adn));
        a00 += w0 * h2l[(size_t)s0 * 128];
        a10 += w0 * h2l[(size_t)s0 * 128 + 64];
        a01 += w1 * h2l[(size_t)s1 * 128];
        a11 += w1 * h2l[(size_t)s1 * 128 + 64];
        a02 += w2 * h2l[(size_t)s2 * 128];
        a12 += w2 * h2l[(size_t)s2 * 128 + 64];
        a03 += w3 * h2l[(size_t)s3 * 128];
        a13 += w3 * h2l[(size_t)s3 * 128 + 64];
    }
    for (; i < end; ++i) {
        int s = col[i];
        float w = __expf(lrelu(as2[s] + adn));
        a00 += w * h2l[(size_t)s * 128];
        a10 += w * h2l[(size_t)s * 128 + 64];
    }
    out[(size_t)n * 128 + lane] = ((a00 + a01) + (a02 + a03)) * inv + b2[lane];
    out[(size_t)n * 128 + 64 + lane] = ((a10 + a11) + (a12 + a13)) * inv + b2[64 + lane];
}

extern "C" void kernel_launch(void* const* d_in, const int* in_sizes, int n_in,
                              void* d_out, int out_size, void* d_ws, size_t ws_size,
                              hipStream_t stream) {
    const float* x = (const float*)d_in[0];
    const int* ei = (const int*)d_in[1];
    const float* W1 = (const float*)d_in[2];
    const float* asrc1 = (const float*)d_in[3];
    const float* adst1 = (const float*)d_in[4];
    const float* b1 = (const float*)d_in[5];
    const float* W2 = (const float*)d_in[6];
    const float* asrc2 = (const float*)d_in[7];
    const float* adst2 = (const float*)d_in[8];
    const float* b2 = (const float*)d_in[9];
    float* out = (float*)d_out;

    const int Nn = NNODES;
    const int E = in_sizes[1] / 2;
    const int Etot = E + Nn;

    char* w = (char*)d_ws;
    auto alloc = [&](size_t bytes) {
        char* p = w;
        w += (bytes + 255) & ~(size_t)255;
        return p;
    };
    float* h1 = (float*)alloc((size_t)Nn * 64 * 4);
    float* h1a = (float*)alloc((size_t)Nn * 64 * 4);
    float* h2 = (float*)alloc((size_t)Nn * 128 * 4);
    float* as1 = (float*)alloc((size_t)Nn * 8 * 4);
    float* ad1 = (float*)alloc((size_t)Nn * 8 * 4);
    float* as2 = (float*)alloc((size_t)Nn * 4);
    float* ad2 = (float*)alloc((size_t)Nn * 4);
    int* indeg = (int*)alloc((size_t)(Nn + 1) * 4);
    int* indptr = (int*)alloc((size_t)(Nn + 1) * 4);
    int* cursor = (int*)alloc((size_t)Nn * 4);
    int* bsums = (int*)alloc(4096);
    int* col = (int*)alloc((size_t)Etot * 4);

    const int NBLK = (Nn + 2047) / 2048;

    hipMemsetAsync(indeg, 0, (size_t)Nn * 4, stream);
    gemm1_k<<<(Nn + 63) / 64, 256, 0, stream>>>(x, W1, h1, Nn);
    attn1_k<<<(Nn * 8 + 255) / 256, 256, 0, stream>>>(h1, asrc1, adst1, as1, ad1, Nn);
    hist_k<<<(Etot + 255) / 256, 256, 0, stream>>>(ei, E, Etot, indeg);
    scanA_k<<<NBLK, 256, 0, stream>>>(indeg, indptr, bsums, Nn);
    scanB_k<<<1, 64, 0, stream>>>(bsums, NBLK);
    scanC_k<<<NBLK, 256, 0, stream>>>(indptr, bsums, cursor, Nn, Etot);
    fill_k<<<(Etot + 255) / 256, 256, 0, stream>>>(ei, E, Etot, cursor, col);
    agg1_k<<<(Nn + 3) / 4, 256, 0, stream>>>(h1, as1, ad1, indptr, col, b1, h1a, Nn);
    gemm2_k<<<(Nn + 63) / 64, 256, 0, stream>>>(h1a, W2, h2, Nn);
    attn2_k<<<(Nn + 3) / 4, 256, 0, stream>>>(h2, asrc2, adst2, as2, ad2, Nn);
    agg2_k<<<(Nn + 3) / 4, 256, 0, stream>>>(h2, as2, ad2, indptr, col, b2, out, Nn);
}

// Round 5
// 877.949 us; speedup vs baseline: 1.9743x; 1.0276x over previous
//
#include <hip/hip_runtime.h>
#include <math.h>

#define NNODES 100000

__device__ __forceinline__ float lrelu(float v) { return v > 0.f ? v : 0.2f * v; }

// ---------------- GEMM1: h1[N,64] = x[N,512] @ W1[512,64] ----------------
// A-tile stored TRANSPOSED in LDS (xs[k][row]) so the per-thread A fragment is
// a contiguous ds_read_b128. 128x64 block tile, 8x4 per-thread accumulator.
__global__ __launch_bounds__(256) void gemm1_k(const float* __restrict__ x,
                                               const float* __restrict__ W,
                                               float* __restrict__ h1, int Nn) {
    __shared__ float xs[64][132];  // [k][row], 128 rows + 4 pad (16B-aligned rows)
    __shared__ float ws[64][68];   // [k][col], 64 cols + 4 pad
    int r0 = blockIdx.x * 128;
    int t = threadIdx.x;
    int ty = t >> 4, tx = t & 15;  // ty: 8-row strip, tx: 4-col strip
    float acc[8][4] = {};
    for (int kb = 0; kb < 512; kb += 64) {
        for (int l = t; l < 2048; l += 256) {
            int row = l >> 4;
            int c4 = (l & 15) * 4;
            int gr = r0 + row;
            float4 v = make_float4(0.f, 0.f, 0.f, 0.f);
            if (gr < Nn) v = *reinterpret_cast<const float4*>(&x[(size_t)gr * 512 + kb + c4]);
            xs[c4][row] = v.x; xs[c4 + 1][row] = v.y; xs[c4 + 2][row] = v.z; xs[c4 + 3][row] = v.w;
        }
        for (int l = t; l < 1024; l += 256) {
            int row = l >> 4;
            int c4 = (l & 15) * 4;
            *reinterpret_cast<float4*>(&ws[row][c4]) =
                *reinterpret_cast<const float4*>(&W[(size_t)(kb + row) * 64 + c4]);
        }
        __syncthreads();
#pragma unroll 4
        for (int k = 0; k < 64; ++k) {
            float4 a0 = *reinterpret_cast<const float4*>(&xs[k][ty * 8]);
            float4 a1 = *reinterpret_cast<const float4*>(&xs[k][ty * 8 + 4]);
            float4 bv = *reinterpret_cast<const float4*>(&ws[k][tx * 4]);
            float a[8] = {a0.x, a0.y, a0.z, a0.w, a1.x, a1.y, a1.z, a1.w};
            float b[4] = {bv.x, bv.y, bv.z, bv.w};
#pragma unroll
            for (int i = 0; i < 8; ++i)
#pragma unroll
                for (int j = 0; j < 4; ++j) acc[i][j] += a[i] * b[j];
        }
        __syncthreads();
    }
#pragma unroll
    for (int i = 0; i < 8; ++i) {
        int gr = r0 + ty * 8 + i;
        if (gr < Nn) {
            float4 o = make_float4(acc[i][0], acc[i][1], acc[i][2], acc[i][3]);
            *reinterpret_cast<float4*>(&h1[(size_t)gr * 64 + tx * 4]) = o;
        }
    }
}

// ---------------- GEMM2: h2[N,128] = h1a[N,64] @ W2[64,128] ----------------
// Same transposed-A trick. 64x128 tile, 4x(4+4) per-thread accumulator.
__global__ __launch_bounds__(256) void gemm2_k(const float* __restrict__ xin,
                                               const float* __restrict__ W,
                                               float* __restrict__ h2, int Nn) {
    __shared__ float xs[64][68];   // [k][row]
    __shared__ float ws[64][132];  // [k][col 0..127]
    int r0 = blockIdx.x * 64;
    int t = threadIdx.x;
    int ty = t >> 4, tx = t & 15;
    for (int l = t; l < 1024; l += 256) {
        int row = l >> 4;
        int c4 = (l & 15) * 4;
        int gr = r0 + row;
        float4 v = make_float4(0.f, 0.f, 0.f, 0.f);
        if (gr < Nn) v = *reinterpret_cast<const float4*>(&xin[(size_t)gr * 64 + c4]);
        xs[c4][row] = v.x; xs[c4 + 1][row] = v.y; xs[c4 + 2][row] = v.z; xs[c4 + 3][row] = v.w;
    }
    for (int l = t; l < 2048; l += 256) {
        int row = l >> 5;
        int c4 = (l & 31) * 4;
        *reinterpret_cast<float4*>(&ws[row][c4]) =
            *reinterpret_cast<const float4*>(&W[(size_t)row * 128 + c4]);
    }
    __syncthreads();
    float acc0[4][4] = {};
    float acc1[4][4] = {};
#pragma unroll 4
    for (int k = 0; k < 64; ++k) {
        float4 av = *reinterpret_cast<const float4*>(&xs[k][ty * 4]);
        float4 b0v = *reinterpret_cast<const float4*>(&ws[k][tx * 4]);
        float4 b1v = *reinterpret_cast<const float4*>(&ws[k][64 + tx * 4]);
        float a[4] = {av.x, av.y, av.z, av.w};
        float b0[4] = {b0v.x, b0v.y, b0v.z, b0v.w};
        float b1[4] = {b1v.x, b1v.y, b1v.z, b1v.w};
#pragma unroll
        for (int i = 0; i < 4; ++i)
#pragma unroll
            for (int j = 0; j < 4; ++j) {
                acc0[i][j] += a[i] * b0[j];
                acc1[i][j] += a[i] * b1[j];
            }
    }
#pragma unroll
    for (int i = 0; i < 4; ++i) {
        int gr = r0 + ty * 4 + i;
        if (gr < Nn) {
            float4 o0 = make_float4(acc0[i][0], acc0[i][1], acc0[i][2], acc0[i][3]);
            float4 o1 = make_float4(acc1[i][0], acc1[i][1], acc1[i][2], acc1[i][3]);
            *reinterpret_cast<float4*>(&h2[(size_t)gr * 128 + tx * 4]) = o0;
            *reinterpret_cast<float4*>(&h2[(size_t)gr * 128 + 64 + tx * 4]) = o1;
        }
    }
}

// ---------------- attn coef layer 1: as1/ad1 [N,8] ----------------
__global__ __launch_bounds__(256) void attn1_k(const float* __restrict__ h1,
                                               const float* __restrict__ asrc,
                                               const float* __restrict__ adst,
                                               float* __restrict__ as1,
                                               float* __restrict__ ad1, int Nn) {
    int t = blockIdx.x * 256 + threadIdx.x;
    int n = t >> 3, h = t & 7;
    if (n >= Nn) return;
    const float* hp = h1 + (size_t)n * 64 + h * 8;
    float s = 0.f, d = 0.f;
#pragma unroll
    for (int c = 0; c < 8; ++c) {
        float v = hp[c];
        s += v * asrc[h * 8 + c];
        d += v * adst[h * 8 + c];
    }
    as1[(size_t)n * 8 + h] = s;
    ad1[(size_t)n * 8 + h] = d;
}

// ---------------- attn coef layer 2: as2/ad2 [N] ----------------
__global__ __launch_bounds__(256) void attn2_k(const float* __restrict__ h2,
                                               const float* __restrict__ asrc,
                                               const float* __restrict__ adst,
                                               float* __restrict__ as2,
                                               float* __restrict__ ad2, int Nn) {
    int wid = threadIdx.x >> 6, lane = threadIdx.x & 63;
    int n = blockIdx.x * 4 + wid;
    if (n >= Nn) return;
    float v0 = h2[(size_t)n * 128 + lane];
    float v1 = h2[(size_t)n * 128 + 64 + lane];
    float s = v0 * asrc[lane] + v1 * asrc[64 + lane];
    float d = v0 * adst[lane] + v1 * adst[64 + lane];
#pragma unroll
    for (int off = 32; off >= 1; off >>= 1) {
        s += __shfl_xor(s, off);
        d += __shfl_xor(d, off);
    }
    if (lane == 0) { as2[n] = s; ad2[n] = d; }
}

// ---------------- CSR build ----------------
__global__ __launch_bounds__(256) void hist_k(const int* __restrict__ ei, int E, int Etot,
                                              int* __restrict__ indeg) {
    int e = blockIdx.x * 256 + threadIdx.x;
    if (e >= Etot) return;
    int d = (e < E) ? ei[E + e] : (e - E);
    atomicAdd(&indeg[d], 1);
}

__global__ __launch_bounds__(256) void scanA_k(const int* __restrict__ indeg,
                                               int* __restrict__ indptr,
                                               int* __restrict__ bsums, int Nn) {
    __shared__ int sd[256];
    int t = threadIdx.x;
    int i0 = blockIdx.x * 2048 + t * 8;
    int v[8], ex[8];
    int run = 0;
#pragma unroll
    for (int j = 0; j < 8; ++j) {
        int i = i0 + j;
        v[j] = (i < Nn) ? indeg[i] : 0;
        ex[j] = run;
        run += v[j];
    }
    sd[t] = run;
    __syncthreads();
    for (int off = 1; off < 256; off <<= 1) {
        int a = (t >= off) ? sd[t - off] : 0;
        __syncthreads();
        sd[t] += a;
        __syncthreads();
    }
    int texc = sd[t] - run;
#pragma unroll
    for (int j = 0; j < 8; ++j) {
        int i = i0 + j;
        if (i < Nn) indptr[i] = texc + ex[j];
    }
    if (t == 0) bsums[blockIdx.x] = sd[255];
}

__global__ void scanB_k(int* __restrict__ bsums, int nb) {
    if (threadIdx.x == 0 && blockIdx.x == 0) {
        int run = 0;
        for (int b = 0; b < nb; ++b) {
            int x = bsums[b];
            bsums[b] = run;
            run += x;
        }
    }
}

__global__ __launch_bounds__(256) void scanC_k(int* __restrict__ indptr,
                                               const int* __restrict__ bsums,
                                               int* __restrict__ cursor, int Nn, int Etot) {
    int t = threadIdx.x;
    int b = blockIdx.x;
    int base = bsums[b];
    int i0 = b * 2048 + t * 8;
#pragma unroll
    for (int j = 0; j < 8; ++j) {
        int i = i0 + j;
        if (i < Nn) {
            int val = indptr[i] + base;
            indptr[i] = val;
            cursor[i] = val;
        }
    }
    if (b == 0 && t == 0) indptr[Nn] = Etot;
}

__global__ __launch_bounds__(256) void fill_k(const int* __restrict__ ei, int E, int Etot,
                                              int* __restrict__ cursor, int* __restrict__ col) {
    int e = blockIdx.x * 256 + threadIdx.x;
    if (e >= Etot) return;
    int s, d;
    if (e < E) { s = ei[e]; d = ei[E + e]; }
    else { s = e - E; d = e - E; }
    int pos = atomicAdd(&cursor[d], 1);
    col[pos] = s;
}

// ---------------- aggregation layer 1 (8 heads x 8 ch) + bias + ELU ----------------
__global__ __launch_bounds__(256) void agg1_k(const float* __restrict__ h1,
                                              const float* __restrict__ as1,
                                              const float* __restrict__ ad1,
                                              const int* __restrict__ indptr,
                                              const int* __restrict__ col,
                                              const float* __restrict__ b1,
                                              float* __restrict__ h1a, int Nn) {
    int wid = threadIdx.x >> 6, lane = threadIdx.x & 63;
    int n = blockIdx.x * 4 + wid;
    if (n >= Nn) return;
    int beg = indptr[n], end = indptr[n + 1];
    int h = lane & 7, eo = lane >> 3;
    float adn = ad1[(size_t)n * 8 + h];
    float ss = 0.f;
    for (int i = beg + eo; i < end; i += 8) {
        int s = col[i];
        ss += __expf(lrelu(as1[(size_t)s * 8 + h] + adn));
    }
    ss += __shfl_xor(ss, 8);
    ss += __shfl_xor(ss, 16);
    ss += __shfl_xor(ss, 32);
    int hb = lane >> 3;
    float sb = __shfl(ss, hb);
    float ab = __shfl(adn, hb);
    float inv = 1.f / sb;
    const float* __restrict__ h1l = h1 + lane;
    float acc0 = 0.f, acc1 = 0.f, acc2 = 0.f, acc3 = 0.f;
    int i = beg;
    for (; i + 4 <= end; i += 4) {
        int s0 = col[i], s1 = col[i + 1], s2 = col[i + 2], s3 = col[i + 3];
        float w0 = __expf(lrelu(as1[(size_t)s0 * 8 + hb] + ab));
        float w1 = __expf(lrelu(as1[(size_t)s1 * 8 + hb] + ab));
        float w2 = __expf(lrelu(as1[(size_t)s2 * 8 + hb] + ab));
        float w3 = __expf(lrelu(as1[(size_t)s3 * 8 + hb] + ab));
        acc0 += w0 * h1l[(size_t)s0 * 64];
        acc1 += w1 * h1l[(size_t)s1 * 64];
        acc2 += w2 * h1l[(size_t)s2 * 64];
        acc3 += w3 * h1l[(size_t)s3 * 64];
    }
    for (; i < end; ++i) {
        int s = col[i];
        acc0 += __expf(lrelu(as1[(size_t)s * 8 + hb] + ab)) * h1l[(size_t)s * 64];
    }
    float o = ((acc0 + acc1) + (acc2 + acc3)) * inv + b1[lane];
    h1a[(size_t)n * 64 + lane] = o > 0.f ? o : expm1f(o);
}

// ---------------- aggregation layer 2 (1 head x 128 ch) + bias ----------------
__global__ __launch_bounds__(256) void agg2_k(const float* __restrict__ h2,
                                              const float* __restrict__ as2,
                                              const float* __restrict__ ad2,
                                              const int* __restrict__ indptr,
                                              const int* __restrict__ col,
                                              const float* __restrict__ b2,
                                              float* __restrict__ out, int Nn) {
    int wid = threadIdx.x >> 6, lane = threadIdx.x & 63;
    int n = blockIdx.x * 4 + wid;
    if (n >= Nn) return;
    int beg = indptr[n], end = indptr[n + 1];
    float adn = ad2[n];
    float ss = 0.f;
    for (int i = beg + lane; i < end; i += 64) {
        ss += __expf(lrelu(as2[col[i]] + adn));
    }
#pragma unroll
    for (int off = 32; off >= 1; off >>= 1) ss += __shfl_xor(ss, off);
    float inv = 1.f / ss;
    const float* __restrict__ h2l = h2 + lane;
    float a00 = 0.f, a01 = 0.f, a02 = 0.f, a03 = 0.f;
    float a10 = 0.f, a11 = 0.f, a12 = 0.f, a13 = 0.f;
    int i = beg;
    for (; i + 4 <= end; i += 4) {
        int s0 = col[i], s1 = col[i + 1], s2 = col[i + 2], s3 = col[i + 3];
        float w0 = __expf(lrelu(as2[s0] + adn));
        float w1 = __expf(lrelu(as2[s1] + adn));
        float w2 = __expf(lrelu(as2[s2] + adn));
        float w3 = __expf(lrelu(as2[s3] + adn));
        a00 += w0 * h2l[(size_t)s0 * 128];
        a10 += w0 * h2l[(size_t)s0 * 128 + 64];
        a01 += w1 * h2l[(size_t)s1 * 128];
        a11 += w1 * h2l[(size_t)s1 * 128 + 64];
        a02 += w2 * h2l[(size_t)s2 * 128];
        a12 += w2 * h2l[(size_t)s2 * 128 + 64];
        a03 += w3 * h2l[(size_t)s3 * 128];
        a13 += w3 * h2l[(size_t)s3 * 128 + 64];
    }
    for (; i < end; ++i) {
        int s = col[i];
        float w = __expf(lrelu(as2[s] + adn));
        a00 += w * h2l[(size_t)s * 128];
        a10 += w * h2l[(size_t)s * 128 + 64];
    }
    out[(size_t)n * 128 + lane] = ((a00 + a01) + (a02 + a03)) * inv + b2[lane];
    out[(size_t)n * 128 + 64 + lane] = ((a10 + a11) + (a12 + a13)) * inv + b2[64 + lane];
}

extern "C" void kernel_launch(void* const* d_in, const int* in_sizes, int n_in,
                              void* d_out, int out_size, void* d_ws, size_t ws_size,
                              hipStream_t stream) {
    const float* x = (const float*)d_in[0];
    const int* ei = (const int*)d_in[1];
    const float* W1 = (const float*)d_in[2];
    const float* asrc1 = (const float*)d_in[3];
    const float* adst1 = (const float*)d_in[4];
    const float* b1 = (const float*)d_in[5];
    const float* W2 = (const float*)d_in[6];
    const float* asrc2 = (const float*)d_in[7];
    const float* adst2 = (const float*)d_in[8];
    const float* b2 = (const float*)d_in[9];
    float* out = (float*)d_out;

    const int Nn = NNODES;
    const int E = in_sizes[1] / 2;
    const int Etot = E + Nn;

    char* w = (char*)d_ws;
    auto alloc = [&](size_t bytes) {
        char* p = w;
        w += (bytes + 255) & ~(size_t)255;
        return p;
    };
    float* h1 = (float*)alloc((size_t)Nn * 64 * 4);
    float* h1a = (float*)alloc((size_t)Nn * 64 * 4);
    float* h2 = (float*)alloc((size_t)Nn * 128 * 4);
    float* as1 = (float*)alloc((size_t)Nn * 8 * 4);
    float* ad1 = (float*)alloc((size_t)Nn * 8 * 4);
    float* as2 = (float*)alloc((size_t)Nn * 4);
    float* ad2 = (float*)alloc((size_t)Nn * 4);
    int* indeg = (int*)alloc((size_t)(Nn + 1) * 4);
    int* indptr = (int*)alloc((size_t)(Nn + 1) * 4);
    int* cursor = (int*)alloc((size_t)Nn * 4);
    int* bsums = (int*)alloc(4096);
    int* col = (int*)alloc((size_t)Etot * 4);

    const int NBLK = (Nn + 2047) / 2048;

    hipMemsetAsync(indeg, 0, (size_t)Nn * 4, stream);
    gemm1_k<<<(Nn + 127) / 128, 256, 0, stream>>>(x, W1, h1, Nn);
    attn1_k<<<(Nn * 8 + 255) / 256, 256, 0, stream>>>(h1, asrc1, adst1, as1, ad1, Nn);
    hist_k<<<(Etot + 255) / 256, 256, 0, stream>>>(ei, E, Etot, indeg);
    scanA_k<<<NBLK, 256, 0, stream>>>(indeg, indptr, bsums, Nn);
    scanB_k<<<1, 64, 0, stream>>>(bsums, NBLK);
    scanC_k<<<NBLK, 256, 0, stream>>>(indptr, bsums, cursor, Nn, Etot);
    fill_k<<<(Etot + 255) / 256, 256, 0, stream>>>(ei, E, Etot, cursor, col);
    agg1_k<<<(Nn + 3) / 4, 256, 0, stream>>>(h1, as1, ad1, indptr, col, b1, h1a, Nn);
    gemm2_k<<<(Nn + 63) / 64, 256, 0, stream>>>(h1a, W2, h2, Nn);
    attn2_k<<<(Nn + 3) / 4, 256, 0, stream>>>(h2, asrc2, adst2, as2, ad2, Nn);
    agg2_k<<<(Nn + 3) / 4, 256, 0, stream>>>(h2, as2, ad2, indptr, col, b2, out, Nn);
}